// Round 2
// baseline (67.327 us; speedup 1.0000x reference)
//
#include <hip/hip_runtime.h>

// out[n,f,y,x] = sum_{c,kh,kw} W[f,c,kh,kw]*xp[n,c,y+kh,x+kw]
//               - 0.5*(||patch(n,y,x)||^2 + ||W_f||^2)
// x: (8,3,64,64) f32, W: (64,3,5,5) f32, out: (8,64,64,64) f32, K=5, PAD=2
//
// Grid: 8n x 64y x 2 filter-halves = 1024 blocks (4/CU), 256 threads.
// Thread: 8 pixels x 1 filter. ps2 (patch norms) computed cooperatively.

#define CH   3
#define NF   64
#define KK   5
#define PADC 2
#define HH   64
#define WW   64

#define NROWS (CH * KK)   // 15
#define ROWW  68          // 64 + 2*PAD
#define BLKF  32          // filters per block
#define WSTRIDE 124       // f*124 % 32 = f*28 % 32 -> 8 distinct banks per wave

__global__ __launch_bounds__(256) void euclid_conv_kernel(
    const float* __restrict__ x,
    const float* __restrict__ Wt,
    float* __restrict__ out)
{
    __shared__ float xs[NROWS * ROWW];     // 1020 floats: padded input rows
    __shared__ float ws[BLKF * WSTRIDE];   // 3968 floats: weights, kw padded to 8
    __shared__ float rs[NROWS * WW];       // 960: per-row 5-wide window sums of x^2
    __shared__ float ps2s[WW];             // 64: patch norms per output x
    __shared__ float w2s[BLKF];            // 32: ||W_f||^2

    const int t    = threadIdx.x;
    const int blk  = blockIdx.x;           // 0..1023
    const int n    = blk >> 7;
    const int rem  = blk & 127;
    const int y    = rem >> 1;
    const int half = rem & 1;

    // ---- stage padded input rows: xs[(c*5+kh)*68 + col] = xp[n,c,y+kh,col] ----
    for (int idx = t; idx < NROWS * ROWW; idx += 256) {
        int row_id = idx / ROWW;
        int col    = idx - row_id * ROWW;
        int c  = row_id / KK;
        int kh = row_id - c * KK;
        int r  = y + kh - PADC;
        int cx = col - PADC;
        float v = 0.0f;
        if ((unsigned)r < HH && (unsigned)cx < WW)
            v = x[((n * CH + c) * HH + r) * WW + cx];
        xs[idx] = v;
    }

    // ---- stage this block's 32 filters: ws[f*124 + (c*5+kh)*8 + kw] ----
    for (int idx = t; idx < BLKF * 75; idx += 256) {
        int f = idx / 75;
        int d = idx - f * 75;
        int c   = d / 25;
        int r2  = d - c * 25;
        int kh  = r2 / 5;
        int kw  = r2 - kh * 5;
        ws[f * WSTRIDE + (c * KK + kh) * 8 + kw] = Wt[(half * BLKF + f) * 75 + d];
    }
    __syncthreads();

    // ---- cooperative patch-norm, pass 1: rs[rr][x] = sum_kw xs[rr][x+kw]^2 ----
    for (int idx = t; idx < NROWS * WW; idx += 256) {
        int rr = idx >> 6;
        int xx = idx & 63;
        const float* p = &xs[rr * ROWW + xx];
        rs[idx] = p[0]*p[0] + p[1]*p[1] + p[2]*p[2] + p[3]*p[3] + p[4]*p[4];
    }
    __syncthreads();

    // ---- pass 2: column-sum ps2 (threads 0..63) and ||W_f||^2 (64..95) ----
    if (t < WW) {
        float s = 0.0f;
        #pragma unroll
        for (int rr = 0; rr < NROWS; ++rr)
            s += rs[rr * WW + t];
        ps2s[t] = s;
    } else if (t < WW + BLKF) {
        int f = t - WW;
        float s = 0.0f;
        const float* wf = &ws[f * WSTRIDE];
        #pragma unroll
        for (int rr = 0; rr < NROWS; ++rr)
            #pragma unroll
            for (int kw = 0; kw < KK; ++kw) {
                float w = wf[rr * 8 + kw];
                s += w * w;
            }
        w2s[f] = s;
    }
    // no barrier yet: conv below only needs xs/ws (ready since first barrier)

    // ---- conv: 8 pixels x 1 filter per thread ----
    const int p8 = t & 7;
    const int fl = t >> 3;                 // 0..31
    const int x0 = p8 * 8;

    float acc[8];
    #pragma unroll
    for (int i = 0; i < 8; ++i) acc[i] = 0.0f;

    #pragma unroll
    for (int rr = 0; rr < NROWS; ++rr) {
        const float4 a = *(const float4*)&xs[rr * ROWW + x0];
        const float4 b = *(const float4*)&xs[rr * ROWW + x0 + 4];
        const float4 c4 = *(const float4*)&xs[rr * ROWW + x0 + 8];
        const float win[12] = {a.x, a.y, a.z, a.w,
                               b.x, b.y, b.z, b.w,
                               c4.x, c4.y, c4.z, c4.w};
        const float4 w03 = *(const float4*)&ws[fl * WSTRIDE + rr * 8];
        const float  w4  = ws[fl * WSTRIDE + rr * 8 + 4];
        const float wv[5] = {w03.x, w03.y, w03.z, w03.w, w4};
        #pragma unroll
        for (int i = 0; i < 8; ++i)
            #pragma unroll
            for (int kw = 0; kw < KK; ++kw)
                acc[i] += wv[kw] * win[i + kw];
    }

    __syncthreads();   // ps2s, w2s ready

    // ---- epilogue: two float4 stores per thread ----
    const float wsq = w2s[fl];
    const float4 q0 = *(const float4*)&ps2s[x0];
    const float4 q1 = *(const float4*)&ps2s[x0 + 4];
    const int f = half * BLKF + fl;
    float* op = &out[((n * NF + f) * HH + y) * WW + x0];

    float4 o0, o1;
    o0.x = acc[0] - 0.5f * (q0.x + wsq);
    o0.y = acc[1] - 0.5f * (q0.y + wsq);
    o0.z = acc[2] - 0.5f * (q0.z + wsq);
    o0.w = acc[3] - 0.5f * (q0.w + wsq);
    o1.x = acc[4] - 0.5f * (q1.x + wsq);
    o1.y = acc[5] - 0.5f * (q1.y + wsq);
    o1.z = acc[6] - 0.5f * (q1.z + wsq);
    o1.w = acc[7] - 0.5f * (q1.w + wsq);
    *(float4*)&op[0] = o0;
    *(float4*)&op[4] = o1;
}

extern "C" void kernel_launch(void* const* d_in, const int* in_sizes, int n_in,
                              void* d_out, int out_size, void* d_ws, size_t ws_size,
                              hipStream_t stream) {
    const float* x  = (const float*)d_in[0];   // 8*3*64*64
    const float* Wt = (const float*)d_in[1];   // 64*3*5*5
    float* out = (float*)d_out;                // 8*64*64*64
    (void)in_sizes; (void)n_in; (void)out_size; (void)d_ws; (void)ws_size;

    dim3 grid(8 * 64 * 2);   // (n, y, filter-half): 1024 blocks
    dim3 block(256);
    hipLaunchKernelGGL(euclid_conv_kernel, grid, block, 0, stream, x, Wt, out);
}